// Round 12
// baseline (2212.126 us; speedup 1.0000x reference)
//
#include <hip/hip_runtime.h>
#include <hip/hip_bf16.h>
#include <math.h>

namespace {

constexpr int kB = 2;
constexpr int kS = 2048;
constexpr int kH = 4096;
constexpr int kNH = 16;
constexpr int kHD = 256;
constexpr int kLDQ = 12288;  // fused qkv row stride

typedef __attribute__((ext_vector_type(4))) float f32x4;
typedef __attribute__((ext_vector_type(16))) float f32x16;
typedef __attribute__((ext_vector_type(8))) short bf16x8;

__device__ __forceinline__ unsigned short f2bf(float f) {
  unsigned int u = __float_as_uint(f);
  u += 0x7FFFu + ((u >> 16) & 1u);
  return (unsigned short)(u >> 16);
}
__device__ __forceinline__ float bf2f(unsigned short h) {
  return __uint_as_float(((unsigned int)h) << 16);
}
__device__ __forceinline__ void gl2lds16(const void* g, void* l) {
  __builtin_amdgcn_global_load_lds(
      (const __attribute__((address_space(1))) unsigned int*)g,
      (__attribute__((address_space(3))) unsigned int*)l, 16, 0, 0);
}

#define SBAR asm volatile("s_barrier" ::: "memory")
#define LGKM0 asm volatile("s_waitcnt lgkmcnt(0)" ::: "memory")

// ---------------- LayerNorm: x -> h(bf16), out = x (residual init) ---------
__global__ __launch_bounds__(256) void ln_fwd(
    const float* __restrict__ x, const float* __restrict__ gam,
    const float* __restrict__ bet, unsigned short* __restrict__ hout,
    float* __restrict__ outp) {
  int row = blockIdx.x;
  int t = threadIdx.x;
  const float4* xr = (const float4*)(x + (size_t)row * kH);
  float4 v[4];
  float sum = 0.f, sq = 0.f;
#pragma unroll
  for (int i = 0; i < 4; i++) {
    v[i] = xr[t + i * 256];
    sum += v[i].x + v[i].y + v[i].z + v[i].w;
    sq += v[i].x * v[i].x + v[i].y * v[i].y + v[i].z * v[i].z + v[i].w * v[i].w;
  }
#pragma unroll
  for (int o = 32; o > 0; o >>= 1) {
    sum += __shfl_xor(sum, o);
    sq += __shfl_xor(sq, o);
  }
  __shared__ float red[8];
  if ((t & 63) == 0) { red[t >> 6] = sum; red[4 + (t >> 6)] = sq; }
  __syncthreads();
  sum = red[0] + red[1] + red[2] + red[3];
  sq = red[4] + red[5] + red[6] + red[7];
  float mu = sum * (1.f / kH);
  float rstd = rsqrtf(sq * (1.f / kH) - mu * mu + 1e-5f);
  const float4* gp = (const float4*)gam;
  const float4* bp = (const float4*)bet;
  ushort4* hr = (ushort4*)(hout + (size_t)row * kH);
  float4* orow = (float4*)(outp + (size_t)row * kH);
#pragma unroll
  for (int i = 0; i < 4; i++) {
    float4 g = gp[t + i * 256];
    float4 bb = bp[t + i * 256];
    ushort4 hv;
    hv.x = f2bf((v[i].x - mu) * rstd * g.x + bb.x);
    hv.y = f2bf((v[i].y - mu) * rstd * g.y + bb.y);
    hv.z = f2bf((v[i].z - mu) * rstd * g.z + bb.z);
    hv.w = f2bf((v[i].w - mu) * rstd * g.w + bb.w);
    hr[t + i * 256] = hv;
    orow[t + i * 256] = v[i];
  }
}

// ------- transpose-convert: out[n][k] = bf16(in[k][n]) ---------------------
__global__ __launch_bounds__(256) void cvt_t(
    const float* __restrict__ in, int ldin, unsigned short* __restrict__ outp,
    int ldout) {
  __shared__ float tile[32][33];
  int n0 = blockIdx.x * 32, k0 = blockIdx.y * 32;
  int tx = threadIdx.x, ty = threadIdx.y;
#pragma unroll
  for (int i = 0; i < 4; i++)
    tile[ty + i * 8][tx] = in[(size_t)(k0 + ty + i * 8) * ldin + n0 + tx];
  __syncthreads();
#pragma unroll
  for (int i = 0; i < 4; i++)
    outp[(size_t)(n0 + ty + i * 8) * ldout + k0 + tx] =
        f2bf(tile[tx][ty + i * 8]);
}

// ------- v (cols 8192.. of qkv) -> vt [B,NH,HD,S] (bf16) -------------------
__global__ __launch_bounds__(256) void vtrans(
    const unsigned short* __restrict__ qkv, unsigned short* __restrict__ vt) {
  __shared__ unsigned short tile[32][33];
  int bh = blockIdx.z;
  int s0 = blockIdx.x * 32, d0 = blockIdx.y * 32;
  int tx = threadIdx.x, ty = threadIdx.y;
  int b = bh >> 4, h = bh & 15;
  const unsigned short* src =
      qkv + (size_t)(b * kS) * kLDQ + 8192 + h * kHD;
#pragma unroll
  for (int i = 0; i < 4; i++)
    tile[ty + i * 8][tx] = src[(size_t)(s0 + ty + i * 8) * kLDQ + d0 + tx];
  __syncthreads();
  unsigned short* dst = vt + (size_t)bh * kHD * kS;
#pragma unroll
  for (int i = 0; i < 4; i++)
    dst[(size_t)(d0 + ty + i * 8) * kS + s0 + tx] = tile[tx][ty + i * 8];
}

// ------- RoPE (pairs) + q-scale 1/16, in place on fused qkv ----------------
__global__ __launch_bounds__(256) void rope_scale(
    unsigned short* __restrict__ qkv, const int* __restrict__ pos) {
  int idx = blockIdx.x * 256 + threadIdx.x;  // pair index over B*S*NH*(HD/2)
  int j = idx & 127;
  int rowh = idx >> 7;  // b*S*NH + s*NH + h
  int h = rowh & 15;
  int s = (rowh >> 4) & 2047;
  int b = rowh >> 15;
  size_t off = ((size_t)(b * kS + s)) * kLDQ + h * kHD + 2 * j;
  const float SCALE = 0.0625f;  // 1/sqrt(256)
  if (j < 32) {
    int p = pos[b * kS + s];
    float inv = exp2f(-(float)j * (13.287712379549449f / 32.f));  // 10000^(-j/32)
    float fr = (float)p * inv;
    float sn, cs;
    sincosf(fr, &sn, &cs);
    float e = bf2f(qkv[off]), o = bf2f(qkv[off + 1]);
    qkv[off] = f2bf((e * cs - o * sn) * SCALE);
    qkv[off + 1] = f2bf((o * cs + e * sn) * SCALE);
    e = bf2f(qkv[off + 4096]); o = bf2f(qkv[off + 4097]);
    qkv[off + 4096] = f2bf(e * cs - o * sn);
    qkv[off + 4097] = f2bf(o * cs + e * sn);
  } else {
    qkv[off] = f2bf(bf2f(qkv[off]) * SCALE);
    qkv[off + 1] = f2bf(bf2f(qkv[off + 1]) * SCALE);
  }
}

// ======= gemm256w: 256x256, BK=64, 8 waves, 32x32x16 MFMA ==================
// Same staging, LDS layout, and wait schedule as gemm256 (R4-proven);
// inner compute uses v_mfma_f32_32x32x16_bf16 (m119: 2495 vs 2176 TF) —
// 32 MFMA/tile instead of 64 at identical ds_read count (24 b128).
// Per-wave output 128x64: 4 m-frags(32 rows) x 2 n-frags(32 cols).
// A/B frag: row(col)=lane&31, k=(lane>>5)*8+e.  C/D (m74/m101-verified):
// col=lane&31, row=(reg&3)+8*(reg>>2)+4*(lane>>5).
// Region1 computes m-frags 0-1 (aE rows), region2 m-frags 2-3 (aL rows) —
// so the mid-tile vmcnt(8) [forces aL(t)] / boundary vmcnt(2) schedule
// transfers unchanged.
template <int EPI>
__global__ __launch_bounds__(512, 2) void gemm256w(
    const unsigned short* __restrict__ A, int lda,
    const unsigned short* __restrict__ Bt, int ldb, void* __restrict__ Cp,
    int ldc, const float* __restrict__ bias, int K, int gx) {
  __shared__ __align__(16) char lds[131072];
  const int t = threadIdx.x;
  const int lane = t & 63, w = t >> 6;
  const int wm = w >> 2, wn = w & 3;
  const int l31 = lane & 31, l5 = lane >> 5;

  const int nwg = gridDim.x;
  const int orig = blockIdx.x;
  const int wg = (orig & 7) * (nwg >> 3) + (orig >> 3);  // XCD swizzle (nwg%8==0)
  const int bx = wg % gx, by = wg / gx;
  const int m0 = by * 256, n0 = bx * 256;

  const int lr = t >> 3, ch = t & 7;
  const int swk = (ch ^ (lr & 7)) * 8;
  const unsigned short* aE0 = A + (size_t)(m0 + lr) * lda + swk;
  const unsigned short* aE1 = A + (size_t)(m0 + 128 + lr) * lda + swk;
  const unsigned short* aL0 = A + (size_t)(m0 + 64 + lr) * lda + swk;
  const unsigned short* aL1 = A + (size_t)(m0 + 192 + lr) * lda + swk;
  const unsigned short* b00 = Bt + (size_t)(n0 + lr) * ldb + swk;
  const unsigned short* b01 = Bt + (size_t)(n0 + 64 + lr) * ldb + swk;
  const unsigned short* b10 = Bt + (size_t)(n0 + 128 + lr) * ldb + swk;
  const unsigned short* b11 = Bt + (size_t)(n0 + 192 + lr) * ldb + swk;
  const int t16 = t * 16;

  f32x16 acc[4][2];
#pragma unroll
  for (int m = 0; m < 4; m++)
#pragma unroll
    for (int n = 0; n < 2; n++) acc[m][n] = (f32x16)(0.f);

  // prologue: stage tile 0 (B x4, AE x2, AL x2)
  {
    char* b = lds;
    gl2lds16(b00, b + 32768 + t16); b00 += 64;
    gl2lds16(b01, b + 40960 + t16); b01 += 64;
    gl2lds16(b10, b + 49152 + t16); b10 += 64;
    gl2lds16(b11, b + 57344 + t16); b11 += 64;
    gl2lds16(aE0, b + t16);         aE0 += 64;
    gl2lds16(aE1, b + 8192 + t16);  aE1 += 64;
    gl2lds16(aL0, b + 16384 + t16); aL0 += 64;
    gl2lds16(aL1, b + 24576 + t16); aL1 += 64;
  }
  asm volatile("s_waitcnt vmcnt(2)" ::: "memory");  // B+AE resident
  SBAR;

  const int nt = K >> 6;
  for (int kt = 0; kt < nt; ++kt) {
    const char* cur = lds + (kt & 1) * 65536;
    char* nxt = lds + (((kt & 1) ^ 1)) * 65536;
    const bool pre = (kt + 1 < nt);
    // -------- region 1: stage B(t+1); read B frags + A m0/m1; MFMA m0,m1
    if (pre) {
      gl2lds16(b00, nxt + 32768 + t16); b00 += 64;
      gl2lds16(b01, nxt + 40960 + t16); b01 += 64;
      gl2lds16(b10, nxt + 49152 + t16); b10 += 64;
      gl2lds16(b11, nxt + 57344 + t16); b11 += 64;
    }
    bf16x8 bfr[2][4];
#pragma unroll
    for (int n = 0; n < 2; n++)
#pragma unroll
      for (int kk = 0; kk < 4; kk++) {
        int c = wn * 64 + n * 32 + l31;
        int kc = kk * 2 + l5;
        bfr[n][kk] = *(const bf16x8*)(cur + 32768 + (c << 7) +
                                      (((kc ^ (c & 7))) << 4));
      }
    bf16x8 af[2][4];
#pragma unroll
    for (int m = 0; m < 2; m++)
#pragma unroll
      for (int kk = 0; kk < 4; kk++) {
        int q = m * 32 + l31;  // 0..63 (aE rows of band)
        int kc = kk * 2 + l5;
        af[m][kk] = *(const bf16x8*)(cur + ((q & 64) << 8) + wm * 8192 +
                                     ((q & 63) << 7) + ((kc ^ (q & 7)) << 4));
      }
    __builtin_amdgcn_s_setprio(1);
#pragma unroll
    for (int kk = 0; kk < 4; kk++)
#pragma unroll
      for (int m = 0; m < 2; m++)
#pragma unroll
        for (int n = 0; n < 2; n++)
          acc[m][n] = __builtin_amdgcn_mfma_f32_32x32x16_bf16(
              af[m][kk], bfr[n][kk], acc[m][n], 0, 0, 0);
    __builtin_amdgcn_s_setprio(0);
    if (pre) {
      gl2lds16(aE0, nxt + t16);         aE0 += 64;
      gl2lds16(aE1, nxt + 8192 + t16);  aE1 += 64;
      gl2lds16(aL0, nxt + 16384 + t16); aL0 += 64;
      gl2lds16(aL1, nxt + 24576 + t16); aL1 += 64;
    }
    if (pre) asm volatile("s_waitcnt vmcnt(8)" ::: "memory");  // forces aL(t)
    else     asm volatile("s_waitcnt vmcnt(0)" ::: "memory");
    SBAR;
    // -------- region 2: read A m2/m3 (aL rows); MFMA m2,m3
#pragma unroll
    for (int m = 0; m < 2; m++)
#pragma unroll
      for (int kk = 0; kk < 4; kk++) {
        int q = 64 + m * 32 + l31;  // 64..127 (aL rows)
        int kc = kk * 2 + l5;
        af[m][kk] = *(const bf16x8*)(cur + ((q & 64) << 8) + wm * 8192 +
                                     ((q & 63) << 7) + ((kc ^ (q & 7)) << 4));
      }
    __builtin_amdgcn_s_setprio(1);
#pragma unroll
    for (int kk = 0; kk < 4; kk++)
#pragma unroll
      for (int m = 0; m < 2; m++)
#pragma unroll
        for (int n = 0; n < 2; n++)
          acc[2 + m][n] = __builtin_amdgcn_mfma_f32_32x32x16_bf16(
              af[m][kk], bfr[n][kk], acc[2 + m][n], 0, 0, 0);
    __builtin_amdgcn_s_setprio(0);
    LGKM0;
    if (pre) asm volatile("s_waitcnt vmcnt(2)" ::: "memory");  // B+AE(t+1)
    SBAR;
  }

  // epilogue: C/D mapping col=lane&31, row=(j&3)+8*(j>>2)+4*(lane>>5)
  const int ccol0 = n0 + wn * 64 + l31;
#pragma unroll
  for (int m = 0; m < 4; m++) {
    int rbase = m0 + wm * 128 + m * 32 + 4 * l5;
#pragma unroll
    for (int n = 0; n < 2; n++) {
      int col = ccol0 + n * 32;
#pragma unroll
      for (int j = 0; j < 16; j++) {
        int row = rbase + (j & 3) + 8 * (j >> 2);
        float v = acc[m][n][j];
        size_t idx = (size_t)row * ldc + col;
        if constexpr (EPI == 0) {
          ((unsigned short*)Cp)[idx] = f2bf(v);
        } else if constexpr (EPI == 1) {
          float u = v + bias[col];
          float c = 0.7978845608028654f * (u + 0.044715f * u * u * u);
          float g = u / (1.0f + __expf(-2.0f * c));
          ((unsigned short*)Cp)[idx] = f2bf(g);
        } else if constexpr (EPI == 2) {
          ((float*)Cp)[idx] += v;
        } else {
          ((float*)Cp)[idx] += v + bias[col];
        }
      }
    }
  }
}

// ======= 256x256 GEMM, BK=64, 8 waves, 16x16x32 (R4-proven control) ========
#define AF_MMA(P)                                                           \
  {                                                                         \
    bf16x8 af_[2][2];                                                       \
    _Pragma("unroll") for (int fm = 0; fm < 2; fm++)                        \
        _Pragma("unroll") for (int kk = 0; kk < 2; kk++) {                  \
      int q_ = (2 * (P) + fm) * 16 + l15;                                   \
      af_[fm][kk] = *(const bf16x8*)(cur + ((q_ & 64) << 8) + wm * 8192 +   \
                                     ((q_ & 63) << 7) +                     \
                                     ((((kk << 2) | l4) ^ key) << 4));      \
    }                                                                       \
    __builtin_amdgcn_s_setprio(1);                                          \
    _Pragma("unroll") for (int fm = 0; fm < 2; fm++)                        \
        _Pragma("unroll") for (int fn = 0; fn < 4; fn++)                    \
            _Pragma("unroll") for (int kk = 0; kk < 2; kk++)                \
      acc[2 * (P) + fm][fn] = __builtin_amdgcn_mfma_f32_16x16x32_bf16(      \
          af_[fm][kk], bfr[fn][kk], acc[2 * (P) + fm][fn], 0, 0, 0);        \
    __builtin_amdgcn_s_setprio(0);                                          \
  }

template <int EPI>
__global__ __launch_bounds__(512, 2) void gemm256(
    const unsigned short* __restrict__ A, int lda,
    const unsigned short* __restrict__ Bt, int ldb, void* __restrict__ Cp,
    int ldc, const float* __restrict__ bias, int K, int gx) {
  __shared__ __align__(16) char lds[131072];
  const int t = threadIdx.x;
  const int lane = t & 63, w = t >> 6;
  const int wm = w >> 2, wn = w & 3;
  const int l15 = lane & 15, l4 = lane >> 4;
  const int key = l15 & 7;

  const int nwg = gridDim.x;
  const int orig = blockIdx.x;
  const int wg = (orig & 7) * (nwg >> 3) + (orig >> 3);
  const int bx = wg % gx, by = wg / gx;
  const int m0 = by * 256, n0 = bx * 256;

  const int lr = t >> 3, ch = t & 7;
  const int swk = (ch ^ (lr & 7)) * 8;
  const unsigned short* aE0 = A + (size_t)(m0 + lr) * lda + swk;
  const unsigned short* aE1 = A + (size_t)(m0 + 128 + lr) * lda + swk;
  const unsigned short* aL0 = A + (size_t)(m0 + 64 + lr) * lda + swk;
  const unsigned short* aL1 = A + (size_t)(m0 + 192 + lr) * lda + swk;
  const unsigned short* b00 = Bt + (size_t)(n0 + lr) * ldb + swk;
  const unsigned short* b01 = Bt + (size_t)(n0 + 64 + lr) * ldb + swk;
  const unsigned short* b10 = Bt + (size_t)(n0 + 128 + lr) * ldb + swk;
  const unsigned short* b11 = Bt + (size_t)(n0 + 192 + lr) * ldb + swk;
  const int t16 = t * 16;

  f32x4 acc[8][4];
#pragma unroll
  for (int m = 0; m < 8; m++)
#pragma unroll
    for (int n = 0; n < 4; n++) acc[m][n] = (f32x4)(0.f);

  {
    char* b = lds;
    gl2lds16(b00, b + 32768 + t16); b00 += 64;
    gl2lds16(b01, b + 40960 + t16); b01 += 64;
    gl2lds16(b10, b + 49152 + t16); b10 += 64;
    gl2lds16(b11, b + 57344 + t16); b11 += 64;
    gl2lds16(aE0, b + t16);         aE0 += 64;
    gl2lds16(aE1, b + 8192 + t16);  aE1 += 64;
    gl2lds16(aL0, b + 16384 + t16); aL0 += 64;
    gl2lds16(aL1, b + 24576 + t16); aL1 += 64;
  }
  asm volatile("s_waitcnt vmcnt(2)" ::: "memory");
  SBAR;

  const int nt = K >> 6;
  for (int kt = 0; kt < nt; ++kt) {
    const char* cur = lds + (kt & 1) * 65536;
    char* nxt = lds + (((kt & 1) ^ 1)) * 65536;
    const bool pre = (kt + 1 < nt);
    bf16x8 bfr[4][2];
    if (pre) {
      gl2lds16(b00, nxt + 32768 + t16); b00 += 64;
      gl2lds16(b01, nxt + 40960 + t16); b01 += 64;
      gl2lds16(b10, nxt + 49152 + t16); b10 += 64;
      gl2lds16(b11, nxt + 57344 + t16); b11 += 64;
    }
#pragma unroll
    for (int fn = 0; fn < 4; fn++)
#pragma unroll
      for (int kk = 0; kk < 2; kk++) {
        int n = wn * 64 + fn * 16 + l15;
        bfr[fn][kk] = *(const bf16x8*)(cur + 32768 + (n << 7) +
                                       ((((kk << 2) | l4) ^ key) << 4));
      }
    AF_MMA(0)
    if (pre) {
      gl2lds16(aE0, nxt + t16);         aE0 += 64;
      gl2lds16(aE1, nxt + 8192 + t16);  aE1 += 64;
      gl2lds16(aL0, nxt + 16384 + t16); aL0 += 64;
      gl2lds16(aL1, nxt + 24576 + t16); aL1 += 64;
    }
    AF_MMA(1)
    if (pre) asm volatile("s_waitcnt vmcnt(8)" ::: "memory");
    else     asm volatile("s_waitcnt vmcnt(0)" ::: "memory");
    SBAR;
    AF_MMA(2)
    AF_MMA(3)
    LGKM0;
    if (pre) asm volatile("s_waitcnt vmcnt(2)" ::: "memory");
    SBAR;
  }

  const int crow = m0 + wm * 128 + l4 * 4;
  const int ccol = n0 + wn * 64 + l15;
#pragma unroll
  for (int m = 0; m < 8; m++) {
#pragma unroll
    for (int n = 0; n < 4; n++) {
      int col = ccol + n * 16;
#pragma unroll
      for (int r = 0; r < 4; r++) {
        int row = crow + m * 16 + r;
        float v = acc[m][n][r];
        size_t idx = (size_t)row * ldc + col;
        if constexpr (EPI == 0) {
          ((unsigned short*)Cp)[idx] = f2bf(v);
        } else if constexpr (EPI == 1) {
          float u = v + bias[col];
          float c = 0.7978845608028654f * (u + 0.044715f * u * u * u);
          float g = u / (1.0f + __expf(-2.0f * c));
          ((unsigned short*)Cp)[idx] = f2bf(g);
        } else if constexpr (EPI == 2) {
          ((float*)Cp)[idx] += v;
        } else {
          ((float*)Cp)[idx] += v + bias[col];
        }
      }
    }
  }
}

// ======= flash attention: 8 waves, QBLK=128, KVBLK=64, pipelined ===========
__global__ __launch_bounds__(512) void attn_fwd(
    const unsigned short* __restrict__ qkv, const unsigned short* __restrict__ vt,
    const int* __restrict__ amask, unsigned short* __restrict__ ctx) {
  __shared__ __align__(16) char alds[147456];
  const int t = threadIdx.x, lane = t & 63, w = t >> 6;
  const int bid = blockIdx.x;
  const int qb = 15 - (bid >> 5);       // heavy-first
  const int bh = bid & 31;
  const int b = bh >> 4, h = bh & 15;
  const int l15 = lane & 15, l4 = lane >> 4;
  const int qbase = qb * 128;

  bf16x8 qf[8];
  {
    int qrow = qbase + w * 16 + l15;
    const unsigned short* qp =
        qkv + (size_t)(b * kS + qrow) * kLDQ + h * kHD + l4 * 8;
#pragma unroll
    for (int ks = 0; ks < 8; ks++) qf[ks] = *(const bf16x8*)(qp + ks * 32);
  }
  f32x4 o[16];
#pragma unroll
  for (int nf = 0; nf < 16; nf++) o[nf] = (f32x4)(0.f);
  float mr[4] = {-INFINITY, -INFINITY, -INFINITY, -INFINITY};
  float lr[4] = {0.f, 0.f, 0.f, 0.f};

  const unsigned short* kbase =
      qkv + (size_t)(b * kS) * kLDQ + 4096 + h * kHD;
  const unsigned short* vbase = vt + (size_t)bh * kHD * kS;
  unsigned short* sPw = (unsigned short*)(alds + 131072 + w * 2048);
  const int nt = 2 * qb + 2;

  const int krow = t >> 5, kch = t & 31;
  const int kcs = (kch ^ (krow & 7)) * 8;
  const int vrow = t >> 3, vch = t & 7;
  const int vcs = (vch ^ (vrow & 7)) * 8;
  const int t16b = t * 16;

#define ATTN_STAGE(KV0, BUF)                                                 \
  {                                                                          \
    char* kd = alds + (BUF) * 32768;                                         \
    char* vd = alds + 65536 + (BUF) * 32768;                                 \
    _Pragma("unroll") for (int i = 0; i < 4; i++) {                          \
      gl2lds16(kbase + (size_t)((KV0) + krow + i * 16) * kLDQ + kcs,         \
               kd + i * 8192 + t16b);                                        \
      gl2lds16(vbase + (size_t)(vrow + i * 64) * kS + (KV0) + vcs,           \
               vd + i * 8192 + t16b);                                        \
    }                                                                        \
  }

  ATTN_STAGE(0, 0)

  for (int kvt = 0; kvt < nt; kvt++) {
    const int kv0 = kvt * 64;
    const int cb = kvt & 1;
    if (kvt + 1 < nt) {
      ATTN_STAGE(kv0 + 64, cb ^ 1)
      asm volatile("s_waitcnt vmcnt(8)" ::: "memory");
    } else {
      asm volatile("s_waitcnt vmcnt(0)" ::: "memory");
    }
    asm volatile("s_barrier" ::: "memory");

    const unsigned short* sK = (const unsigned short*)(alds + cb * 32768);
    const unsigned short* sV =
        (const unsigned short*)(alds + 65536 + cb * 32768);

    f32x4 sc[4];
#pragma unroll
    for (int g = 0; g < 4; g++) sc[g] = (f32x4)(0.f);
    __builtin_amdgcn_s_setprio(1);
#pragma unroll
    for (int g = 0; g < 4; g++) {
      int row = g * 16 + l15;
#pragma unroll
      for (int ks = 0; ks < 8; ks++) {
        bf16x8 kf =
            *(const bf16x8*)&sK[row * 256 + (((ks * 4 + l4) ^ (row & 7)) * 8)];
        sc[g] = __builtin_amdgcn_mfma_f32_16x16x32_bf16(qf[ks], kf, sc[g], 0, 0, 0);
      }
    }
    __builtin_amdgcn_s_setprio(0);

    int am[4];
#pragma unroll
    for (int g = 0; g < 4; g++) am[g] = amask[b * kS + kv0 + g * 16 + l15];
    float mx[4];
#pragma unroll
    for (int r = 0; r < 4; r++) {
      int qi = qbase + w * 16 + l4 * 4 + r;
      float a = -INFINITY;
#pragma unroll
      for (int g = 0; g < 4; g++) {
        bool ok = (kv0 + g * 16 + l15 <= qi) && (am[g] != 0);
        float s = ok ? sc[g][r] : -INFINITY;
        sc[g][r] = s;
        a = fmaxf(a, s);
      }
#pragma unroll
      for (int d = 1; d < 16; d <<= 1) a = fmaxf(a, __shfl_xor(a, d));
      mx[r] = a;
    }
    bool nd = false;
#pragma unroll
    for (int r = 0; r < 4; r++) nd |= (mx[r] > mr[r] + 8.f);
    if (__any(nd)) {
#pragma unroll
      for (int r = 0; r < 4; r++) {
        float nm = fmaxf(mr[r], mx[r]);
        float c = __expf(mr[r] - nm);
        lr[r] *= c;
        mr[r] = nm;
#pragma unroll
        for (int nf = 0; nf < 16; nf++) o[nf][r] *= c;
      }
    }
#pragma unroll
    for (int r = 0; r < 4; r++) {
      int prow = l4 * 4 + r;
      int pkey = (prow ^ (prow >> 2)) & 7;
      float rs = 0.f;
#pragma unroll
      for (int g = 0; g < 4; g++) {
        float p = __expf(sc[g][r] - mr[r]);
        rs += p;
        int kvl = g * 16 + l15;
        sPw[prow * 64 + (((kvl >> 3) ^ pkey) << 3) + (kvl & 7)] = f2bf(p);
      }
#pragma unroll
      for (int d = 1; d < 16; d <<= 1) rs += __shfl_xor(rs, d);
      lr[r] += rs;
    }
    asm volatile("s_waitcnt lgkmcnt(0)" ::: "memory");

    int rkey = (l15 ^ (l15 >> 2)) & 7;
    bf16x8 pa[2];
#pragma unroll
    for (int ks2 = 0; ks2 < 2; ks2++)
      pa[ks2] = *(const bf16x8*)&sPw[l15 * 64 + (((ks2 * 4 + l4) ^ rkey) << 3)];
    __builtin_amdgcn_s_setprio(1);
#pragma unroll
    for (int nf = 0; nf < 16; nf++) {
      int vr = nf * 16 + l15;
#pragma unroll
      for (int ks2 = 0; ks2 < 2; ks2++) {
        bf16x8 vf =
            *(const bf16x8*)&sV[vr * 64 + (((ks2 * 4 + l4) ^ (vr & 7)) * 8)];
        o[nf] = __builtin_amdgcn_mfma_f32_16x16x32_bf16(pa[ks2], vf, o[nf], 0, 0, 0);
      }
    }
    __builtin_amdgcn_s_setprio(0);
    asm volatile("s_barrier" ::: "memory");
  }

  float invl[4];
#pragma unroll
  for (int r = 0; r < 4; r++) invl[r] = 1.0f / lr[r];
#pragma unroll
  for (int nf = 0; nf < 16; nf++) {
    int d = nf * 16 + l15;
#pragma unroll
    for (int r = 0; r < 4; r++) {
      int qi = qbase + w * 16 + l4 * 4 + r;
      ctx[(size_t)(b * kS + qi) * kH + h * kHD + d] = f2bf(o[nf][r] * invl[r]);
    }
  }
#undef ATTN_STAGE
}

}  // namespace

extern "C" void kernel_launch(void* const* d_in, const int* in_sizes, int n_in,
                              void* d_out, int out_size, void* d_ws,
                              size_t ws_size, hipStream_t stream) {
  const float* x = (const float*)d_in[0];
  const int* amask = (const int*)d_in[1];
  const int* pos = (const int*)d_in[2];
  const float* lns = (const float*)d_in[3];
  const float* lnb = (const float*)d_in[4];
  const float* wq = (const float*)d_in[5];
  const float* wk = (const float*)d_in[6];
  const float* wv = (const float*)d_in[7];
  const float* wo = (const float*)d_in[8];
  const float* w_in = (const float*)d_in[9];
  const float* b_in = (const float*)d_in[10];
  const float* w_out = (const float*)d_in[11];
  const float* b_out = (const float*)d_in[12];
  float* out = (float*)d_out;

  if (ws_size < 268435456ull) return;  // need 256 MiB scratch
  unsigned short* ws = (unsigned short*)d_ws;
  unsigned short* h_bf = ws;
  unsigned short* wqkvT = ws + 16777216;
  unsigned short* qkv = ws + 67108864;
  unsigned short* vtb = ws + 117440512;
  unsigned short* ctxb = ws + 16777216;
  unsigned short* woT = ws + 33554432;
  unsigned short* w_inT = ws + 33554432;
  unsigned short* mid = ws + 67108864;
  unsigned short* w_outT = ws;

  dim3 t256(256);
  dim3 t512(512);
  dim3 t32x8(32, 8);

  // 1. LayerNorm -> h (bf16); out = x
  ln_fwd<<<kB * kS, t256, 0, stream>>>(x, lns, lnb, h_bf, out);

  // 2. fused QKV: qkv = h @ [wq wk wv]   (32x32 MFMA variant)
  cvt_t<<<dim3(128, 128), t32x8, 0, stream>>>(wq, 4096, wqkvT, 4096);
  cvt_t<<<dim3(128, 128), t32x8, 0, stream>>>(wk, 4096, wqkvT + 16777216, 4096);
  cvt_t<<<dim3(128, 128), t32x8, 0, stream>>>(wv, 4096, wqkvT + 33554432, 4096);
  gemm256w<0><<<dim3(768), t512, 0, stream>>>(h_bf, 4096, wqkvT, 4096,
                                              qkv, kLDQ, nullptr, 4096, 48);
  // 3. RoPE + q-scale, V transpose
  rope_scale<<<32768, t256, 0, stream>>>(qkv, pos);
  vtrans<<<dim3(64, 8, 32), t32x8, 0, stream>>>(qkv, vtb);
  // 4. attention -> ctx
  attn_fwd<<<dim3(512), t512, 0, stream>>>(qkv, vtb, amask, ctxb);
  // 5. out += ctx @ wo   (16x16 gemm256 control)
  cvt_t<<<dim3(128, 128), t32x8, 0, stream>>>(wo, 4096, woT, 4096);
  gemm256<2><<<dim3(256), t512, 0, stream>>>(ctxb, 4096, woT, 4096, out,
                                             4096, nullptr, 4096, 16);
  // 6. MLP first GEMM (two N-halves, 32x32): mid = gelu(h @ w_in + b_in)
  for (int c = 0; c < 2; c++) {
    cvt_t<<<dim3(256, 128), t32x8, 0, stream>>>(w_in + c * 8192, 16384, w_inT,
                                                4096);
    gemm256w<1><<<dim3(512), t512, 0, stream>>>(
        h_bf, 4096, w_inT, 4096, mid + c * 8192, 16384, b_in + c * 8192, 4096,
        32);
  }
  // 7. MLP second GEMM (single, K=16384, 32x32)
  cvt_t<<<dim3(128, 512), t32x8, 0, stream>>>(w_out, 4096, w_outT, 16384);
  gemm256w<3><<<dim3(256), t512, 0, stream>>>(mid, 16384, w_outT, 16384, out,
                                              4096, b_out, 16384, 16);
}

// Round 13
// 1944.011 us; speedup vs baseline: 1.1379x; 1.1379x over previous
//
#include <hip/hip_runtime.h>
#include <hip/hip_bf16.h>
#include <math.h>

namespace {

constexpr int kB = 2;
constexpr int kS = 2048;
constexpr int kH = 4096;
constexpr int kNH = 16;
constexpr int kHD = 256;
constexpr int kLDQ = 12288;  // fused qkv row stride

typedef __attribute__((ext_vector_type(4))) float f32x4;
typedef __attribute__((ext_vector_type(8))) short bf16x8;

__device__ __forceinline__ unsigned short f2bf(float f) {
  unsigned int u = __float_as_uint(f);
  u += 0x7FFFu + ((u >> 16) & 1u);
  return (unsigned short)(u >> 16);
}
__device__ __forceinline__ float bf2f(unsigned short h) {
  return __uint_as_float(((unsigned int)h) << 16);
}
__device__ __forceinline__ void gl2lds16(const void* g, void* l) {
  __builtin_amdgcn_global_load_lds(
      (const __attribute__((address_space(1))) unsigned int*)g,
      (__attribute__((address_space(3))) unsigned int*)l, 16, 0, 0);
}

#define SBAR asm volatile("s_barrier" ::: "memory")
#define LGKM0 asm volatile("s_waitcnt lgkmcnt(0)" ::: "memory")

// ---------------- LayerNorm: x -> h(bf16), out = x (residual init) ---------
__global__ __launch_bounds__(256) void ln_fwd(
    const float* __restrict__ x, const float* __restrict__ gam,
    const float* __restrict__ bet, unsigned short* __restrict__ hout,
    float* __restrict__ outp) {
  int row = blockIdx.x;
  int t = threadIdx.x;
  const float4* xr = (const float4*)(x + (size_t)row * kH);
  float4 v[4];
  float sum = 0.f, sq = 0.f;
#pragma unroll
  for (int i = 0; i < 4; i++) {
    v[i] = xr[t + i * 256];
    sum += v[i].x + v[i].y + v[i].z + v[i].w;
    sq += v[i].x * v[i].x + v[i].y * v[i].y + v[i].z * v[i].z + v[i].w * v[i].w;
  }
#pragma unroll
  for (int o = 32; o > 0; o >>= 1) {
    sum += __shfl_xor(sum, o);
    sq += __shfl_xor(sq, o);
  }
  __shared__ float red[8];
  if ((t & 63) == 0) { red[t >> 6] = sum; red[4 + (t >> 6)] = sq; }
  __syncthreads();
  sum = red[0] + red[1] + red[2] + red[3];
  sq = red[4] + red[5] + red[6] + red[7];
  float mu = sum * (1.f / kH);
  float rstd = rsqrtf(sq * (1.f / kH) - mu * mu + 1e-5f);
  const float4* gp = (const float4*)gam;
  const float4* bp = (const float4*)bet;
  ushort4* hr = (ushort4*)(hout + (size_t)row * kH);
  float4* orow = (float4*)(outp + (size_t)row * kH);
#pragma unroll
  for (int i = 0; i < 4; i++) {
    float4 g = gp[t + i * 256];
    float4 bb = bp[t + i * 256];
    ushort4 hv;
    hv.x = f2bf((v[i].x - mu) * rstd * g.x + bb.x);
    hv.y = f2bf((v[i].y - mu) * rstd * g.y + bb.y);
    hv.z = f2bf((v[i].z - mu) * rstd * g.z + bb.z);
    hv.w = f2bf((v[i].w - mu) * rstd * g.w + bb.w);
    hr[t + i * 256] = hv;
    orow[t + i * 256] = v[i];
  }
}

// ------- transpose-convert: out[n][k] = bf16(in[k][n]) ---------------------
__global__ __launch_bounds__(256) void cvt_t(
    const float* __restrict__ in, int ldin, unsigned short* __restrict__ outp,
    int ldout) {
  __shared__ float tile[32][33];
  int n0 = blockIdx.x * 32, k0 = blockIdx.y * 32;
  int tx = threadIdx.x, ty = threadIdx.y;
#pragma unroll
  for (int i = 0; i < 4; i++)
    tile[ty + i * 8][tx] = in[(size_t)(k0 + ty + i * 8) * ldin + n0 + tx];
  __syncthreads();
#pragma unroll
  for (int i = 0; i < 4; i++)
    outp[(size_t)(n0 + ty + i * 8) * ldout + k0 + tx] =
        f2bf(tile[tx][ty + i * 8]);
}

// ------- v (cols 8192.. of qkv) -> vt [B,NH,HD,S] (bf16) -------------------
__global__ __launch_bounds__(256) void vtrans(
    const unsigned short* __restrict__ qkv, unsigned short* __restrict__ vt) {
  __shared__ unsigned short tile[32][33];
  int bh = blockIdx.z;
  int s0 = blockIdx.x * 32, d0 = blockIdx.y * 32;
  int tx = threadIdx.x, ty = threadIdx.y;
  int b = bh >> 4, h = bh & 15;
  const unsigned short* src =
      qkv + (size_t)(b * kS) * kLDQ + 8192 + h * kHD;
#pragma unroll
  for (int i = 0; i < 4; i++)
    tile[ty + i * 8][tx] = src[(size_t)(s0 + ty + i * 8) * kLDQ + d0 + tx];
  __syncthreads();
  unsigned short* dst = vt + (size_t)bh * kHD * kS;
#pragma unroll
  for (int i = 0; i < 4; i++)
    dst[(size_t)(d0 + ty + i * 8) * kS + s0 + tx] = tile[tx][ty + i * 8];
}

// ------- RoPE (pairs) + q-scale 1/16, in place on fused qkv ----------------
__global__ __launch_bounds__(256) void rope_scale(
    unsigned short* __restrict__ qkv, const int* __restrict__ pos) {
  int idx = blockIdx.x * 256 + threadIdx.x;  // pair index over B*S*NH*(HD/2)
  int j = idx & 127;
  int rowh = idx >> 7;  // b*S*NH + s*NH + h
  int h = rowh & 15;
  int s = (rowh >> 4) & 2047;
  int b = rowh >> 15;
  size_t off = ((size_t)(b * kS + s)) * kLDQ + h * kHD + 2 * j;
  const float SCALE = 0.0625f;  // 1/sqrt(256)
  if (j < 32) {
    int p = pos[b * kS + s];
    float inv = exp2f(-(float)j * (13.287712379549449f / 32.f));  // 10000^(-j/32)
    float fr = (float)p * inv;
    float sn, cs;
    sincosf(fr, &sn, &cs);
    float e = bf2f(qkv[off]), o = bf2f(qkv[off + 1]);
    qkv[off] = f2bf((e * cs - o * sn) * SCALE);
    qkv[off + 1] = f2bf((o * cs + e * sn) * SCALE);
    e = bf2f(qkv[off + 4096]); o = bf2f(qkv[off + 4097]);
    qkv[off + 4096] = f2bf(e * cs - o * sn);
    qkv[off + 4097] = f2bf(o * cs + e * sn);
  } else {
    qkv[off] = f2bf(bf2f(qkv[off]) * SCALE);
    qkv[off + 1] = f2bf(bf2f(qkv[off + 1]) * SCALE);
  }
}

// ======= 256x256 GEMM, BK=64, 8 waves, 2-barrier/tile deep pipeline ========
// (R4/R9-proven best: ~980-1030 TF, MfmaUtil ~50%, VGPR 104, 0 conflicts)
#define AF_MMA(P)                                                           \
  {                                                                         \
    bf16x8 af_[2][2];                                                       \
    _Pragma("unroll") for (int fm = 0; fm < 2; fm++)                        \
        _Pragma("unroll") for (int kk = 0; kk < 2; kk++) {                  \
      int q_ = (2 * (P) + fm) * 16 + l15;                                   \
      af_[fm][kk] = *(const bf16x8*)(cur + ((q_ & 64) << 8) + wm * 8192 +   \
                                     ((q_ & 63) << 7) +                     \
                                     ((((kk << 2) | l4) ^ key) << 4));      \
    }                                                                       \
    __builtin_amdgcn_s_setprio(1);                                          \
    _Pragma("unroll") for (int fm = 0; fm < 2; fm++)                        \
        _Pragma("unroll") for (int fn = 0; fn < 4; fn++)                    \
            _Pragma("unroll") for (int kk = 0; kk < 2; kk++)                \
      acc[2 * (P) + fm][fn] = __builtin_amdgcn_mfma_f32_16x16x32_bf16(      \
          af_[fm][kk], bfr[fn][kk], acc[2 * (P) + fm][fn], 0, 0, 0);        \
    __builtin_amdgcn_s_setprio(0);                                          \
  }

template <int EPI>
__global__ __launch_bounds__(512, 2) void gemm256(
    const unsigned short* __restrict__ A, int lda,
    const unsigned short* __restrict__ Bt, int ldb, void* __restrict__ Cp,
    int ldc, const float* __restrict__ bias, int K, int gx) {
  __shared__ __align__(16) char lds[131072];
  const int t = threadIdx.x;
  const int lane = t & 63, w = t >> 6;
  const int wm = w >> 2, wn = w & 3;
  const int l15 = lane & 15, l4 = lane >> 4;
  const int key = l15 & 7;

  const int nwg = gridDim.x;
  const int orig = blockIdx.x;
  const int wg = (orig & 7) * (nwg >> 3) + (orig >> 3);  // XCD swizzle (nwg%8==0)
  const int bx = wg % gx, by = wg / gx;
  const int m0 = by * 256, n0 = bx * 256;

  const int lr = t >> 3, ch = t & 7;
  const int swk = (ch ^ (lr & 7)) * 8;
  const unsigned short* aE0 = A + (size_t)(m0 + lr) * lda + swk;
  const unsigned short* aE1 = A + (size_t)(m0 + 128 + lr) * lda + swk;
  const unsigned short* aL0 = A + (size_t)(m0 + 64 + lr) * lda + swk;
  const unsigned short* aL1 = A + (size_t)(m0 + 192 + lr) * lda + swk;
  const unsigned short* b00 = Bt + (size_t)(n0 + lr) * ldb + swk;
  const unsigned short* b01 = Bt + (size_t)(n0 + 64 + lr) * ldb + swk;
  const unsigned short* b10 = Bt + (size_t)(n0 + 128 + lr) * ldb + swk;
  const unsigned short* b11 = Bt + (size_t)(n0 + 192 + lr) * ldb + swk;
  const int t16 = t * 16;

  f32x4 acc[8][4];
#pragma unroll
  for (int m = 0; m < 8; m++)
#pragma unroll
    for (int n = 0; n < 4; n++) acc[m][n] = (f32x4)(0.f);

  // prologue: stage tile 0 (order: B x4, AE x2, AL x2)
  {
    char* b = lds;
    gl2lds16(b00, b + 32768 + t16); b00 += 64;
    gl2lds16(b01, b + 40960 + t16); b01 += 64;
    gl2lds16(b10, b + 49152 + t16); b10 += 64;
    gl2lds16(b11, b + 57344 + t16); b11 += 64;
    gl2lds16(aE0, b + t16);         aE0 += 64;
    gl2lds16(aE1, b + 8192 + t16);  aE1 += 64;
    gl2lds16(aL0, b + 16384 + t16); aL0 += 64;
    gl2lds16(aL1, b + 24576 + t16); aL1 += 64;
  }
  asm volatile("s_waitcnt vmcnt(2)" ::: "memory");  // B+AE resident
  SBAR;

  const int nt = K >> 6;
  for (int kt = 0; kt < nt; ++kt) {
    const char* cur = lds + (kt & 1) * 65536;
    char* nxt = lds + (((kt & 1) ^ 1)) * 65536;
    const bool pre = (kt + 1 < nt);
    bf16x8 bfr[4][2];
    // -------- region 1: stage B(t+1); read B-frags + A-q0; MFMA q0
    if (pre) {
      gl2lds16(b00, nxt + 32768 + t16); b00 += 64;
      gl2lds16(b01, nxt + 40960 + t16); b01 += 64;
      gl2lds16(b10, nxt + 49152 + t16); b10 += 64;
      gl2lds16(b11, nxt + 57344 + t16); b11 += 64;
    }
#pragma unroll
    for (int fn = 0; fn < 4; fn++)
#pragma unroll
      for (int kk = 0; kk < 2; kk++) {
        int n = wn * 64 + fn * 16 + l15;
        bfr[fn][kk] = *(const bf16x8*)(cur + 32768 + (n << 7) +
                                       ((((kk << 2) | l4) ^ key) << 4));
      }
    AF_MMA(0)
    // stage A(t+1); MFMA q1
    if (pre) {
      gl2lds16(aE0, nxt + t16);         aE0 += 64;
      gl2lds16(aE1, nxt + 8192 + t16);  aE1 += 64;
      gl2lds16(aL0, nxt + 16384 + t16); aL0 += 64;
      gl2lds16(aL1, nxt + 24576 + t16); aL1 += 64;
    }
    AF_MMA(1)
    if (pre) asm volatile("s_waitcnt vmcnt(8)" ::: "memory");  // forces AL(t)
    else     asm volatile("s_waitcnt vmcnt(0)" ::: "memory");
    SBAR;
    // -------- region 2: MFMA q2, q3 (read AL of cur)
    AF_MMA(2)
    AF_MMA(3)
    LGKM0;
    if (pre) asm volatile("s_waitcnt vmcnt(2)" ::: "memory");  // B+AE(t+1)
    SBAR;
  }

  const int crow = m0 + wm * 128 + l4 * 4;
  const int ccol = n0 + wn * 64 + l15;
#pragma unroll
  for (int m = 0; m < 8; m++) {
#pragma unroll
    for (int n = 0; n < 4; n++) {
      int col = ccol + n * 16;
#pragma unroll
      for (int r = 0; r < 4; r++) {
        int row = crow + m * 16 + r;
        float v = acc[m][n][r];
        size_t idx = (size_t)row * ldc + col;
        if constexpr (EPI == 0) {
          ((unsigned short*)Cp)[idx] = f2bf(v);
        } else if constexpr (EPI == 1) {
          float u = v + bias[col];
          float c = 0.7978845608028654f * (u + 0.044715f * u * u * u);
          float g = u / (1.0f + __expf(-2.0f * c));
          ((unsigned short*)Cp)[idx] = f2bf(g);
        } else if constexpr (EPI == 2) {
          ((float*)Cp)[idx] += v;
        } else {
          ((float*)Cp)[idx] += v + bias[col];
        }
      }
    }
  }
}

// ======= flash attention: 8 waves, QBLK=128, KVBLK=64, pipelined ===========
// q,k read from fused qkv (stride kLDQ, k at col offset 4096); ctx stride kH.
__global__ __launch_bounds__(512) void attn_fwd(
    const unsigned short* __restrict__ qkv, const unsigned short* __restrict__ vt,
    const int* __restrict__ amask, unsigned short* __restrict__ ctx) {
  __shared__ __align__(16) char alds[147456];
  const int t = threadIdx.x, lane = t & 63, w = t >> 6;
  const int bid = blockIdx.x;
  const int qb = 15 - (bid >> 5);       // heavy-first
  const int bh = bid & 31;
  const int b = bh >> 4, h = bh & 15;
  const int l15 = lane & 15, l4 = lane >> 4;
  const int qbase = qb * 128;

  bf16x8 qf[8];
  {
    int qrow = qbase + w * 16 + l15;
    const unsigned short* qp =
        qkv + (size_t)(b * kS + qrow) * kLDQ + h * kHD + l4 * 8;
#pragma unroll
    for (int ks = 0; ks < 8; ks++) qf[ks] = *(const bf16x8*)(qp + ks * 32);
  }
  f32x4 o[16];
#pragma unroll
  for (int nf = 0; nf < 16; nf++) o[nf] = (f32x4)(0.f);
  float mr[4] = {-INFINITY, -INFINITY, -INFINITY, -INFINITY};
  float lr[4] = {0.f, 0.f, 0.f, 0.f};

  const unsigned short* kbase =
      qkv + (size_t)(b * kS) * kLDQ + 4096 + h * kHD;
  const unsigned short* vbase = vt + (size_t)bh * kHD * kS;
  unsigned short* sPw = (unsigned short*)(alds + 131072 + w * 2048);
  const int nt = 2 * qb + 2;

  const int krow = t >> 5, kch = t & 31;
  const int kcs = (kch ^ (krow & 7)) * 8;
  const int vrow = t >> 3, vch = t & 7;
  const int vcs = (vch ^ (vrow & 7)) * 8;
  const int t16b = t * 16;

#define ATTN_STAGE(KV0, BUF)                                                 \
  {                                                                          \
    char* kd = alds + (BUF) * 32768;                                         \
    char* vd = alds + 65536 + (BUF) * 32768;                                 \
    _Pragma("unroll") for (int i = 0; i < 4; i++) {                          \
      gl2lds16(kbase + (size_t)((KV0) + krow + i * 16) * kLDQ + kcs,         \
               kd + i * 8192 + t16b);                                        \
      gl2lds16(vbase + (size_t)(vrow + i * 64) * kS + (KV0) + vcs,           \
               vd + i * 8192 + t16b);                                        \
    }                                                                        \
  }

  ATTN_STAGE(0, 0)

  for (int kvt = 0; kvt < nt; kvt++) {
    const int kv0 = kvt * 64;
    const int cb = kvt & 1;
    if (kvt + 1 < nt) {
      ATTN_STAGE(kv0 + 64, cb ^ 1)
      asm volatile("s_waitcnt vmcnt(8)" ::: "memory");
    } else {
      asm volatile("s_waitcnt vmcnt(0)" ::: "memory");
    }
    asm volatile("s_barrier" ::: "memory");

    const unsigned short* sK = (const unsigned short*)(alds + cb * 32768);
    const unsigned short* sV =
        (const unsigned short*)(alds + 65536 + cb * 32768);

    f32x4 sc[4];
#pragma unroll
    for (int g = 0; g < 4; g++) sc[g] = (f32x4)(0.f);
    __builtin_amdgcn_s_setprio(1);
#pragma unroll
    for (int g = 0; g < 4; g++) {
      int row = g * 16 + l15;
#pragma unroll
      for (int ks = 0; ks < 8; ks++) {
        bf16x8 kf =
            *(const bf16x8*)&sK[row * 256 + (((ks * 4 + l4) ^ (row & 7)) * 8)];
        sc[g] = __builtin_amdgcn_mfma_f32_16x16x32_bf16(qf[ks], kf, sc[g], 0, 0, 0);
      }
    }
    __builtin_amdgcn_s_setprio(0);

    int am[4];
#pragma unroll
    for (int g = 0; g < 4; g++) am[g] = amask[b * kS + kv0 + g * 16 + l15];
    float mx[4];
#pragma unroll
    for (int r = 0; r < 4; r++) {
      int qi = qbase + w * 16 + l4 * 4 + r;
      float a = -INFINITY;
#pragma unroll
      for (int g = 0; g < 4; g++) {
        bool ok = (kv0 + g * 16 + l15 <= qi) && (am[g] != 0);
        float s = ok ? sc[g][r] : -INFINITY;
        sc[g][r] = s;
        a = fmaxf(a, s);
      }
#pragma unroll
      for (int d = 1; d < 16; d <<= 1) a = fmaxf(a, __shfl_xor(a, d));
      mx[r] = a;
    }
    bool nd = false;
#pragma unroll
    for (int r = 0; r < 4; r++) nd |= (mx[r] > mr[r] + 8.f);
    if (__any(nd)) {
#pragma unroll
      for (int r = 0; r < 4; r++) {
        float nm = fmaxf(mr[r], mx[r]);
        float c = __expf(mr[r] - nm);
        lr[r] *= c;
        mr[r] = nm;
#pragma unroll
        for (int nf = 0; nf < 16; nf++) o[nf][r] *= c;
      }
    }
#pragma unroll
    for (int r = 0; r < 4; r++) {
      int prow = l4 * 4 + r;
      int pkey = (prow ^ (prow >> 2)) & 7;
      float rs = 0.f;
#pragma unroll
      for (int g = 0; g < 4; g++) {
        float p = __expf(sc[g][r] - mr[r]);
        rs += p;
        int kvl = g * 16 + l15;
        sPw[prow * 64 + (((kvl >> 3) ^ pkey) << 3) + (kvl & 7)] = f2bf(p);
      }
#pragma unroll
      for (int d = 1; d < 16; d <<= 1) rs += __shfl_xor(rs, d);
      lr[r] += rs;
    }
    asm volatile("s_waitcnt lgkmcnt(0)" ::: "memory");

    int rkey = (l15 ^ (l15 >> 2)) & 7;
    bf16x8 pa[2];
#pragma unroll
    for (int ks2 = 0; ks2 < 2; ks2++)
      pa[ks2] = *(const bf16x8*)&sPw[l15 * 64 + (((ks2 * 4 + l4) ^ rkey) << 3)];
    __builtin_amdgcn_s_setprio(1);
#pragma unroll
    for (int nf = 0; nf < 16; nf++) {
      int vr = nf * 16 + l15;
#pragma unroll
      for (int ks2 = 0; ks2 < 2; ks2++) {
        bf16x8 vf =
            *(const bf16x8*)&sV[vr * 64 + (((ks2 * 4 + l4) ^ (vr & 7)) * 8)];
        o[nf] = __builtin_amdgcn_mfma_f32_16x16x32_bf16(pa[ks2], vf, o[nf], 0, 0, 0);
      }
    }
    __builtin_amdgcn_s_setprio(0);
    asm volatile("s_barrier" ::: "memory");
  }

  float invl[4];
#pragma unroll
  for (int r = 0; r < 4; r++) invl[r] = 1.0f / lr[r];
#pragma unroll
  for (int nf = 0; nf < 16; nf++) {
    int d = nf * 16 + l15;
#pragma unroll
    for (int r = 0; r < 4; r++) {
      int qi = qbase + w * 16 + l4 * 4 + r;
      ctx[(size_t)(b * kS + qi) * kH + h * kHD + d] = f2bf(o[nf][r] * invl[r]);
    }
  }
#undef ATTN_STAGE
}

}  // namespace

extern "C" void kernel_launch(void* const* d_in, const int* in_sizes, int n_in,
                              void* d_out, int out_size, void* d_ws,
                              size_t ws_size, hipStream_t stream) {
  const float* x = (const float*)d_in[0];
  const int* amask = (const int*)d_in[1];
  const int* pos = (const int*)d_in[2];
  const float* lns = (const float*)d_in[3];
  const float* lnb = (const float*)d_in[4];
  const float* wq = (const float*)d_in[5];
  const float* wk = (const float*)d_in[6];
  const float* wv = (const float*)d_in[7];
  const float* wo = (const float*)d_in[8];
  const float* w_in = (const float*)d_in[9];
  const float* b_in = (const float*)d_in[10];
  const float* w_out = (const float*)d_in[11];
  const float* b_out = (const float*)d_in[12];
  float* out = (float*)d_out;

  if (ws_size < 268435456ull) return;  // need 256 MiB scratch
  unsigned short* ws = (unsigned short*)d_ws;
  // workspace (units: shorts; 16M shorts = 32MB):
  //  h      @0        (16M)   alive until end of MLP1
  //  wqkvT  @16M      (48M)   attn phase        | ctx @16M (16M) after
  //  qkv    @64M      (48M)   attn phase
  //  vtb    @112M     (16M)   attn phase
  //  woT    @32M      (8M)    wo phase (inside dead wqkvT tail)
  //  w_inT  @32M..64M (32M)   MLP1 phase (half) | mid @64M..128M (64M)
  //  w_outT @0..64M   (64M)   MLP2 phase (h dead)
  unsigned short* h_bf = ws;
  unsigned short* wqkvT = ws + 16777216;
  unsigned short* qkv = ws + 67108864;
  unsigned short* vtb = ws + 117440512;
  unsigned short* ctxb = ws + 16777216;
  unsigned short* woT = ws + 33554432;
  unsigned short* w_inT = ws + 33554432;
  unsigned short* mid = ws + 67108864;
  unsigned short* w_outT = ws;

  dim3 t256(256);
  dim3 t512(512);
  dim3 t32x8(32, 8);

  // 1. LayerNorm -> h (bf16); out = x
  ln_fwd<<<kB * kS, t256, 0, stream>>>(x, lns, lnb, h_bf, out);

  // 2. fused QKV: qkv = h @ [wq wk wv]
  cvt_t<<<dim3(128, 128), t32x8, 0, stream>>>(wq, 4096, wqkvT, 4096);
  cvt_t<<<dim3(128, 128), t32x8, 0, stream>>>(wk, 4096, wqkvT + 16777216, 4096);
  cvt_t<<<dim3(128, 128), t32x8, 0, stream>>>(wv, 4096, wqkvT + 33554432, 4096);
  gemm256<0><<<dim3(768), t512, 0, stream>>>(h_bf, 4096, wqkvT, 4096,
                                             qkv, kLDQ, nullptr, 4096, 48);
  // 3. RoPE + q-scale, V transpose
  rope_scale<<<32768, t256, 0, stream>>>(qkv, pos);
  vtrans<<<dim3(64, 8, 32), t32x8, 0, stream>>>(qkv, vtb);
  // 4. attention -> ctx
  attn_fwd<<<dim3(512), t512, 0, stream>>>(qkv, vtb, amask, ctxb);
  // 5. out += ctx @ wo
  cvt_t<<<dim3(128, 128), t32x8, 0, stream>>>(wo, 4096, woT, 4096);
  gemm256<2><<<dim3(256), t512, 0, stream>>>(ctxb, 4096, woT, 4096, out,
                                             4096, nullptr, 4096, 16);
  // 6. MLP first GEMM (two N-halves): mid = gelu(h @ w_in + b_in)
  for (int c = 0; c < 2; c++) {
    cvt_t<<<dim3(256, 128), t32x8, 0, stream>>>(w_in + c * 8192, 16384, w_inT,
                                                4096);
    gemm256<1><<<dim3(512), t512, 0, stream>>>(
        h_bf, 4096, w_inT, 4096, mid + c * 8192, 16384, b_in + c * 8192, 4096,
        32);
  }
  // 7. MLP second GEMM (single, K=16384): out += mid @ w_out + b_out
  cvt_t<<<dim3(128, 512), t32x8, 0, stream>>>(w_out, 4096, w_outT, 16384);
  gemm256<3><<<dim3(256), t512, 0, stream>>>(mid, 16384, w_outT, 16384, out,
                                             4096, b_out, 16384, 16);
}